// Round 11
// baseline (96.656 us; speedup 1.0000x reference)
//
#include <hip/hip_runtime.h>

typedef __attribute__((ext_vector_type(8)))  __bf16 bf16x8;
typedef __attribute__((ext_vector_type(4)))  __bf16 bf16x4;
typedef __attribute__((ext_vector_type(16))) float  f32x16;

constexpr int NG  = 2048;
constexpr int NN  = 64;
constexpr int DD  = 128;
constexpr int KK  = 128;
constexpr int OUTD = 10;

// upper-triangular 32x32 tile list: t -> (ti, tj), ti <= tj
__device__ __host__ inline void tileOf(int t, int& ti, int& tj) {
    if (t < 4)      { ti = 0; tj = t;     }
    else if (t < 7) { ti = 1; tj = t - 3; }
    else if (t < 9) { ti = 2; tj = t - 5; }
    else            { ti = 3; tj = 3;     }
}

// XtL: 64-elem rows -> XOR elem bits 3-5 with row&7
__device__ inline int xtIdx(int r, int c) { return r * 64  + (c ^ ((r & 7) << 3)); }
// GL: 128-elem rows -> XOR elem bits 3-6 with row&15
__device__ inline int gIdx (int r, int c) { return r * 128 + (c ^ ((r & 15) << 3)); }

#define WAVE_REDUCE(v)                      \
    v += __shfl_down(v, 32, 64);            \
    v += __shfl_down(v, 16, 64);            \
    v += __shfl_down(v, 8, 64);             \
    v += __shfl_down(v, 4, 64);             \
    v += __shfl_down(v, 2, 64);             \
    v += __shfl_down(v, 1, 64);

// ---------------------------------------------------------------------------
// Kernel 1a: A[o][f][e] = sum_k Wa[k,f]*W1[o,k*D+e]; c[o][e] = sum_k b[k]*W1[o,k*D+e]
// ---------------------------------------------------------------------------
__global__ __launch_bounds__(128)
void precompute_kernel(const float* __restrict__ Wa,
                       const float* __restrict__ b_att,
                       const float* __restrict__ W1,
                       float* __restrict__ A,
                       float* __restrict__ c)
{
    const int o = blockIdx.x >> 7;
    const int f = blockIdx.x & 127;
    const int e = threadIdx.x;
    const float* __restrict__ W1o = W1 + (size_t)o * (KK * DD);

    float acc = 0.f, cacc = 0.f;
    for (int k = 0; k < KK; ++k) {
        const float w1 = W1o[k * DD + e];
        acc  += Wa[k * DD + f] * w1;
        cacc += b_att[k] * w1;
    }
    A[((size_t)o * DD + f) * DD + e] = acc;
    if (f == 0) c[o * DD + e] = cacc;
}

// ---------------------------------------------------------------------------
// Kernel 1b (proven): symmetrized S packed in 32x32 D-fragment order, bf16,
// diag-tile upper part zeroed in memory.
//   Sp[((o*10+t)*64 + lane)*16 + r] = S[ti*32 + (r&3)+8*(r>>2)+4*(lane>>5), tj*32 + (lane&31)]
// ---------------------------------------------------------------------------
__global__ __launch_bounds__(256)
void pack_kernel(const float* __restrict__ A, __bf16* __restrict__ Sp)
{
    const int b = blockIdx.x;
    const int o = b / 10, t = b - o * 10;
    int ti, tj; tileOf(t, ti, tj);
    const int l  = threadIdx.x & 63;
    const int rq = threadIdx.x >> 6;      // 0..3
    const int e  = tj * 32 + (l & 31);
    const float* __restrict__ Ao = A + (size_t)o * DD * DD;

    bf16x4 p;
#pragma unroll
    for (int j = 0; j < 4; ++j) {
        const int f = ti * 32 + j + 8 * rq + 4 * (l >> 5);
        float v;
        if (f < e)       v = Ao[f * DD + e] + Ao[e * DD + f];
        else if (f == e) v = Ao[f * DD + f];
        else             v = 0.f;
        p[j] = (__bf16)v;
    }
    *(bf16x4*)&Sp[(size_t)((o * 10 + t) * 64 + l) * 16 + rq * 4] = p;
}

// ---------------------------------------------------------------------------
// Kernel 2: one block per TWO graphs, 1024 threads = 16 waves, 5 barriers.
// LDS: XtL 16K + GL 32K + sp 4K + red 880B = ~53.9 KB.
// Gram: wave w -> tile (w&3, w>>2), 4 MFMA. H: 10 upper-tri tiles:
// graph A on waves 0-9 (ph3A/ph4A), graph B on waves 6-15 (tile w-6).
// colsum+c.s: wave 15 (A), wave 14 (B). Output: per-wave shfl -> red -> 20 thr.
// ---------------------------------------------------------------------------
__global__ __launch_bounds__(1024)
void graph_kernel(const float* __restrict__ x,
                  const __bf16* __restrict__ Sp,
                  const float* __restrict__ cg,
                  const float* __restrict__ bias1,
                  float* __restrict__ out)
{
    __shared__ __align__(16) __bf16 XtL[DD * NN];   // 16 KB
    __shared__ __align__(16) __bf16 GL [DD * DD];   // 32 KB
    __shared__ float sp[8][DD];                     // 4 KB
    __shared__ float red[2][OUTD][11];              // 880 B

    const int g0  = blockIdx.x * 2;
    const int g1  = g0 + 1;
    const int tid = threadIdx.x;
    const int w   = tid >> 6;          // 0..15
    const int l   = tid & 63;
    const int l31 = l & 31;
    const int l5  = l >> 5;
    const int f   = tid & 127;         // 0..127
    const int seg = tid >> 7;          // 0..7
    const float* __restrict__ xgA = x + (size_t)g0 * NN * DD;
    const float* __restrict__ xgB = x + (size_t)g1 * NN * DD;

    const int gi = w & 3, gj = w >> 2;

    // ---- ph0A: load 8 rows of X_A (col f), store X^T bf16 ----
    {
        float v[8];
#pragma unroll
        for (int i = 0; i < 8; ++i) v[i] = xgA[(seg * 8 + i) * DD + f];
        bf16x8 p;
#pragma unroll
        for (int i = 0; i < 8; ++i) p[i] = (__bf16)v[i];
        *(bf16x8*)&XtL[xtIdx(f, seg * 8)] = p;
    }
    __syncthreads();   // B1: XtL(A) ready

    // ---- ph1A: gram tile (gi,gj), 4 MFMA ----
    f32x16 acc;
#pragma unroll
    for (int i = 0; i < 16; ++i) acc[i] = 0.f;
    {
        const int ar = gi * 32 + l31, br = gj * 32 + l31;
#pragma unroll
        for (int ks = 0; ks < 4; ++ks) {
            const int kc = ks * 16 + l5 * 8;
            bf16x8 a = *(const bf16x8*)&XtL[xtIdx(ar, kc)];
            bf16x8 b = *(const bf16x8*)&XtL[xtIdx(br, kc)];
            acc = __builtin_amdgcn_mfma_f32_32x32x16_bf16(a, b, acc, 0, 0, 0);
        }
    }
    // issue graph B's x loads (latency hides under ph2A + B2 + ph3A)
    float vB[8];
#pragma unroll
    for (int i = 0; i < 8; ++i) vB[i] = xgB[(seg * 8 + i) * DD + f];

    // ---- ph2A: quantize -> GL transposed + sp partial ----
    {
        float sum = 0.f;
        const int e = gj * 32 + l31;
#pragma unroll
        for (int g2 = 0; g2 < 4; ++g2) {
            bf16x4 p;
#pragma unroll
            for (int j = 0; j < 4; ++j) {
                const float q = rintf(acc[g2 * 4 + j] * 100.f) * 0.01f;
                p[j] = (__bf16)q;
                sum += q;
            }
            *(bf16x4*)&GL[gIdx(e, gi * 32 + g2 * 8 + l5 * 4)] = p;
        }
        sp[gi * 2 + l5][e] = sum;
    }
    __syncthreads();   // B2: GL(A)+sp(A) ready; XtL(A) reads done

    // ---- segment: XtL(B) store; ph3A (w<10); wave 15: colsumA + csA ----
    {
        bf16x8 p;
#pragma unroll
        for (int i = 0; i < 8; ++i) p[i] = (__bf16)vB[i];
        *(bf16x8*)&XtL[xtIdx(f, seg * 8)] = p;
    }
    f32x16 hacc;
#pragma unroll
    for (int i = 0; i < 16; ++i) hacc[i] = 0.f;
    if (w < 10) {
        int ht, hj; tileOf(w, ht, hj);
        const int ra = ht * 32 + l31, rb = hj * 32 + l31;
#pragma unroll
        for (int ks = 0; ks < 8; ++ks) {
            const int kc = ks * 16 + l5 * 8;
            bf16x8 a = *(const bf16x8*)&GL[gIdx(ra, kc)];
            bf16x8 b = *(const bf16x8*)&GL[gIdx(rb, kc)];
            hacc = __builtin_amdgcn_mfma_f32_32x32x16_bf16(a, b, hacc, 0, 0, 0);
        }
    }
    if (w == 15) {   // colsum A + c.s term
        float slo = 0.f, shi = 0.f;
#pragma unroll
        for (int i = 0; i < 8; ++i) { slo += sp[i][l]; shi += sp[i][64 + l]; }
#pragma unroll
        for (int o = 0; o < OUTD; ++o) {
            float v = cg[o * DD + l] * slo + cg[o * DD + 64 + l] * shi;
            WAVE_REDUCE(v)
            if (l == 0) red[0][o][10] = v;
        }
    }
    __syncthreads();   // B3: XtL(B) ready; GL(A)+sp(A) reads done

    // ---- ph4A (w<10): contract hacc with Sp tile w -> red[0][o][w] ----
    if (w < 10) {
#pragma unroll
        for (int o = 0; o < OUTD; ++o) {
            const __bf16* __restrict__ spp = Sp + (size_t)((o * 10 + w) * 64 + l) * 16;
            const bf16x8 s0 = *(const bf16x8*)&spp[0];
            const bf16x8 s1 = *(const bf16x8*)&spp[8];
            float t = 0.f;
#pragma unroll
            for (int j = 0; j < 8; ++j) t += (float)s0[j] * hacc[j];
#pragma unroll
            for (int j = 0; j < 8; ++j) t += (float)s1[j] * hacc[8 + j];
            WAVE_REDUCE(t)
            if (l == 0) red[0][o][w] = t;
        }
    }

    // ---- ph1B: gram tile (gi,gj) on XtL(B) ----
#pragma unroll
    for (int i = 0; i < 16; ++i) acc[i] = 0.f;
    {
        const int ar = gi * 32 + l31, br = gj * 32 + l31;
#pragma unroll
        for (int ks = 0; ks < 4; ++ks) {
            const int kc = ks * 16 + l5 * 8;
            bf16x8 a = *(const bf16x8*)&XtL[xtIdx(ar, kc)];
            bf16x8 b = *(const bf16x8*)&XtL[xtIdx(br, kc)];
            acc = __builtin_amdgcn_mfma_f32_32x32x16_bf16(a, b, acc, 0, 0, 0);
        }
    }
    // ---- ph2B: quantize -> GL transposed + sp partial ----
    {
        float sum = 0.f;
        const int e = gj * 32 + l31;
#pragma unroll
        for (int g2 = 0; g2 < 4; ++g2) {
            bf16x4 p;
#pragma unroll
            for (int j = 0; j < 4; ++j) {
                const float q = rintf(acc[g2 * 4 + j] * 100.f) * 0.01f;
                p[j] = (__bf16)q;
                sum += q;
            }
            *(bf16x4*)&GL[gIdx(e, gi * 32 + g2 * 8 + l5 * 4)] = p;
        }
        sp[gi * 2 + l5][e] = sum;
    }
    __syncthreads();   // B4: GL(B)+sp(B) ready

    // ---- ph3B (w>=6): H tile (w-6); wave 14: colsumB + csB ----
#pragma unroll
    for (int i = 0; i < 16; ++i) hacc[i] = 0.f;
    if (w >= 6) {
        int ht, hj; tileOf(w - 6, ht, hj);
        const int ra = ht * 32 + l31, rb = hj * 32 + l31;
#pragma unroll
        for (int ks = 0; ks < 8; ++ks) {
            const int kc = ks * 16 + l5 * 8;
            bf16x8 a = *(const bf16x8*)&GL[gIdx(ra, kc)];
            bf16x8 b = *(const bf16x8*)&GL[gIdx(rb, kc)];
            hacc = __builtin_amdgcn_mfma_f32_32x32x16_bf16(a, b, hacc, 0, 0, 0);
        }
    }
    if (w == 14) {   // colsum B + c.s term
        float slo = 0.f, shi = 0.f;
#pragma unroll
        for (int i = 0; i < 8; ++i) { slo += sp[i][l]; shi += sp[i][64 + l]; }
#pragma unroll
        for (int o = 0; o < OUTD; ++o) {
            float v = cg[o * DD + l] * slo + cg[o * DD + 64 + l] * shi;
            WAVE_REDUCE(v)
            if (l == 0) red[1][o][10] = v;
        }
    }

    // ---- ph4B (w>=6): contract -> red[1][o][w-6] (wave-local, no barrier) ----
    if (w >= 6) {
        const int t2 = w - 6;
#pragma unroll
        for (int o = 0; o < OUTD; ++o) {
            const __bf16* __restrict__ spp = Sp + (size_t)((o * 10 + t2) * 64 + l) * 16;
            const bf16x8 s0 = *(const bf16x8*)&spp[0];
            const bf16x8 s1 = *(const bf16x8*)&spp[8];
            float t = 0.f;
#pragma unroll
            for (int j = 0; j < 8; ++j) t += (float)s0[j] * hacc[j];
#pragma unroll
            for (int j = 0; j < 8; ++j) t += (float)s1[j] * hacc[8 + j];
            WAVE_REDUCE(t)
            if (l == 0) red[1][o][t2] = t;
        }
    }
    __syncthreads();   // B5: all red slots written

    // ---- final: 20 threads sum 11 slots + bias ----
    if (tid < 2 * OUTD) {
        const int g = tid / OUTD, o = tid - g * OUTD;
        float v = bias1[o];
#pragma unroll
        for (int s2 = 0; s2 < 11; ++s2) v += red[g][o][s2];
        out[(size_t)(g ? g1 : g0) * OUTD + o] = v;
    }
}

// ---------------------------------------------------------------------------
extern "C" void kernel_launch(void* const* d_in, const int* in_sizes, int n_in,
                              void* d_out, int out_size, void* d_ws, size_t ws_size,
                              hipStream_t stream)
{
    const float* x     = (const float*)d_in[0];
    const float* Wa    = (const float*)d_in[1];
    const float* b_att = (const float*)d_in[2];
    const float* W1    = (const float*)d_in[3];
    const float* bias1 = (const float*)d_in[4];
    float* out = (float*)d_out;

    float*  A  = (float*)d_ws;                       // 163840 f32 (640 KB)
    float*  c  = A + (size_t)OUTD * DD * DD;         // 1280 f32
    __bf16* Sp = (__bf16*)(c + OUTD * DD);           // 102400 bf16 (200 KB)

    precompute_kernel<<<OUTD * DD, 128, 0, stream>>>(Wa, b_att, W1, A, c);
    pack_kernel<<<100, 256, 0, stream>>>(A, Sp);
    graph_kernel<<<NG / 2, 1024, 0, stream>>>(x, Sp, c, bias1, out);
}

// Round 12
// 84.017 us; speedup vs baseline: 1.1504x; 1.1504x over previous
//
#include <hip/hip_runtime.h>

typedef __attribute__((ext_vector_type(8)))  __bf16 bf16x8;
typedef __attribute__((ext_vector_type(4)))  __bf16 bf16x4;
typedef __attribute__((ext_vector_type(16))) float  f32x16;

constexpr int NG  = 2048;
constexpr int NN  = 64;
constexpr int DD  = 128;
constexpr int KK  = 128;
constexpr int OUTD = 10;

// upper-triangular 32x32 tile list: t -> (ti, tj), ti <= tj
__device__ __host__ inline void tileOf(int t, int& ti, int& tj) {
    if (t < 4)      { ti = 0; tj = t;     }
    else if (t < 7) { ti = 1; tj = t - 3; }
    else if (t < 9) { ti = 2; tj = t - 5; }
    else            { ti = 3; tj = 3;     }
}

// XtL: 64-elem rows -> XOR elem bits 3-5 with row&7
__device__ inline int xtIdx(int r, int c) { return r * 64  + (c ^ ((r & 7) << 3)); }
// GL: 128-elem rows -> XOR elem bits 3-6 with row&15
__device__ inline int gIdx (int r, int c) { return r * 128 + (c ^ ((r & 15) << 3)); }

// ---------------------------------------------------------------------------
// Kernel 1a: A[o][f][e] = sum_k Wa[k,f]*W1[o,k*D+e]; c[o][e] = sum_k b[k]*W1[o,k*D+e]
// ---------------------------------------------------------------------------
__global__ __launch_bounds__(128)
void precompute_kernel(const float* __restrict__ Wa,
                       const float* __restrict__ b_att,
                       const float* __restrict__ W1,
                       float* __restrict__ A,
                       float* __restrict__ c)
{
    const int o = blockIdx.x >> 7;
    const int f = blockIdx.x & 127;
    const int e = threadIdx.x;
    const float* __restrict__ W1o = W1 + (size_t)o * (KK * DD);

    float acc = 0.f, cacc = 0.f;
    for (int k = 0; k < KK; ++k) {
        const float w1 = W1o[k * DD + e];
        acc  += Wa[k * DD + f] * w1;
        cacc += b_att[k] * w1;
    }
    A[((size_t)o * DD + f) * DD + e] = acc;
    if (f == 0) c[o * DD + e] = cacc;
}

// ---------------------------------------------------------------------------
// Kernel 1b (proven): symmetrized S packed in 32x32 D-fragment order, bf16,
// diag-tile upper part zeroed in memory.
//   Sp[((o*10+t)*64 + lane)*16 + r] = S[ti*32 + (r&3)+8*(r>>2)+4*(lane>>5), tj*32 + (lane&31)]
// ---------------------------------------------------------------------------
__global__ __launch_bounds__(256)
void pack_kernel(const float* __restrict__ A, __bf16* __restrict__ Sp)
{
    const int b = blockIdx.x;
    const int o = b / 10, t = b - o * 10;
    int ti, tj; tileOf(t, ti, tj);
    const int l  = threadIdx.x & 63;
    const int rq = threadIdx.x >> 6;      // 0..3
    const int e  = tj * 32 + (l & 31);
    const float* __restrict__ Ao = A + (size_t)o * DD * DD;

    bf16x4 p;
#pragma unroll
    for (int j = 0; j < 4; ++j) {
        const int f = ti * 32 + j + 8 * rq + 4 * (l >> 5);
        float v;
        if (f < e)       v = Ao[f * DD + e] + Ao[e * DD + f];
        else if (f == e) v = Ao[f * DD + f];
        else             v = 0.f;
        p[j] = (__bf16)v;
    }
    *(bf16x4*)&Sp[(size_t)((o * 10 + t) * 64 + l) * 16 + rq * 4] = p;
}

// ---------------------------------------------------------------------------
// One full graph: phases 0-5 including its own contraction and output.
// Accumulator lifetimes are contained (gram acc0/acc1 die at ph2; hacc/hX
// die at ph4) so only ~32 AGPR are ever live.
// ---------------------------------------------------------------------------
__device__ __forceinline__ void do_graph(
    const float* __restrict__ xg,
    __bf16* __restrict__ XtL, __bf16* __restrict__ GL, float* __restrict__ PP,
    float (*__restrict__ sp)[DD], float* __restrict__ sS,
    const __bf16* __restrict__ Sp, const float* __restrict__ cg,
    const float* __restrict__ bias1, float* __restrict__ out, int gidx,
    int tid, int w, int l, int l31, int l5)
{
    const int f = tid & 127, half = tid >> 7;
    const int ti  = w & 3;
    const int tj0 = (w >> 2) * 2;

    // ---- ph0: load X column-wise, store X^T bf16 (RNE) ----
    {
#pragma unroll
        for (int ch = 0; ch < 2; ++ch) {
            float v[8];
#pragma unroll
            for (int i = 0; i < 8; ++i) v[i] = xg[(half * 16 + ch * 8 + i) * DD + f];
            bf16x8 p;
#pragma unroll
            for (int i = 0; i < 8; ++i) p[i] = (__bf16)v[i];
            *(bf16x8*)&XtL[xtIdx(f, half * 16 + ch * 8)] = p;
        }
    }
    __syncthreads();   // B1: XtL ready

    // ---- ph1: gram tiles (ti,tj0), (ti,tj0+1) ----
    f32x16 acc0, acc1;
#pragma unroll
    for (int i = 0; i < 16; ++i) { acc0[i] = 0.f; acc1[i] = 0.f; }
    {
        const int arow  = ti  * 32 + l31;
        const int brow0 = tj0 * 32 + l31;
#pragma unroll
        for (int ks = 0; ks < 4; ++ks) {
            const int kc = ks * 16 + l5 * 8;
            bf16x8 a  = *(const bf16x8*)&XtL[xtIdx(arow, kc)];
            bf16x8 b0 = *(const bf16x8*)&XtL[xtIdx(brow0, kc)];
            bf16x8 b1 = *(const bf16x8*)&XtL[xtIdx(brow0 + 32, kc)];
            acc0 = __builtin_amdgcn_mfma_f32_32x32x16_bf16(a, b0, acc0, 0, 0, 0);
            acc1 = __builtin_amdgcn_mfma_f32_32x32x16_bf16(a, b1, acc1, 0, 0, 0);
        }
    }
    __syncthreads();   // B2: XtL reads done; GL may overwrite

    // ---- ph2: quantize -> GL transposed + sp partials ----
    {
        float sum0 = 0.f, sum1 = 0.f;
#pragma unroll
        for (int tt = 0; tt < 2; ++tt) {
            const int e = (tj0 + tt) * 32 + l31;
#pragma unroll
            for (int g2 = 0; g2 < 4; ++g2) {
                bf16x4 p;
#pragma unroll
                for (int j = 0; j < 4; ++j) {
                    const float av = tt ? acc1[g2 * 4 + j] : acc0[g2 * 4 + j];
                    const float q = rintf(av * 100.f) * 0.01f;
                    p[j] = (__bf16)q;
                    if (tt) sum1 += q; else sum0 += q;
                }
                *(bf16x4*)&GL[gIdx(e, ti * 32 + g2 * 8 + l5 * 4)] = p;
            }
        }
        sp[ti * 2 + l5][tj0 * 32 + l31]       = sum0;
        sp[ti * 2 + l5][(tj0 + 1) * 32 + l31] = sum1;
    }
    __syncthreads();   // B3: GL + sp ready

    // ---- ph2.5 (waves 2,3): colsum ----
    if (w == 2 || w == 3) {
        const int e = (w - 2) * 64 + l;
        float s = 0.f;
#pragma unroll
        for (int i = 0; i < 8; ++i) s += sp[i][e];
        sS[e] = s;
    }

    // ---- ph3: H tiles (tile w on all; tiles 8,9 on waves 6,7 via hX) ----
    f32x16 hacc, hX;
#pragma unroll
    for (int i = 0; i < 16; ++i) { hacc[i] = 0.f; hX[i] = 0.f; }
    {
        int hti, htj; tileOf(w, hti, htj);
        const int ra = hti * 32 + l31, rb = htj * 32 + l31;
#pragma unroll
        for (int ks = 0; ks < 8; ++ks) {
            const int kc = ks * 16 + l5 * 8;
            bf16x8 a = *(const bf16x8*)&GL[gIdx(ra, kc)];
            bf16x8 b = *(const bf16x8*)&GL[gIdx(rb, kc)];
            hacc = __builtin_amdgcn_mfma_f32_32x32x16_bf16(a, b, hacc, 0, 0, 0);
        }
    }
    if (w >= 6) {
        int ti1, tj1; tileOf(8 + (w - 6), ti1, tj1);
        const int ra = ti1 * 32 + l31, rb = tj1 * 32 + l31;
#pragma unroll
        for (int ks = 0; ks < 8; ++ks) {
            const int kc = ks * 16 + l5 * 8;
            bf16x8 a = *(const bf16x8*)&GL[gIdx(ra, kc)];
            bf16x8 b = *(const bf16x8*)&GL[gIdx(rb, kc)];
            hX = __builtin_amdgcn_mfma_f32_32x32x16_bf16(a, b, hX, 0, 0, 0);
        }
    }
    __syncthreads();   // B4: GL reads done (PP may overwrite); sS visible

    // ---- ph4: contraction with Sp (bf16, zeros baked) -> PP ----
#pragma unroll
    for (int o = 0; o < OUTD; ++o) {
        const __bf16* __restrict__ spp = Sp + (size_t)((o * 10 + w) * 64 + l) * 16;
        const bf16x8 s0 = *(const bf16x8*)&spp[0];
        const bf16x8 s1 = *(const bf16x8*)&spp[8];
        float t = 0.f;
#pragma unroll
        for (int j = 0; j < 8; ++j) t += (float)s0[j] * hacc[j];
#pragma unroll
        for (int j = 0; j < 8; ++j) t += (float)s1[j] * hacc[8 + j];
        if (w >= 6) {   // extra tiles 8,9
            const __bf16* __restrict__ sp2 =
                Sp + (size_t)((o * 10 + 8 + (w - 6)) * 64 + l) * 16;
            const bf16x8 e0 = *(const bf16x8*)&sp2[0];
            const bf16x8 e1 = *(const bf16x8*)&sp2[8];
#pragma unroll
            for (int j = 0; j < 8; ++j) t += (float)e0[j] * hX[j];
#pragma unroll
            for (int j = 0; j < 8; ++j) t += (float)e1[j] * hX[8 + j];
        }
        if (w == 0)
            t += cg[o * DD + l] * sS[l] + cg[o * DD + 64 + l] * sS[64 + l];
        PP[o * 512 + tid] = t;
    }
    __syncthreads();   // B5: PP ready

    // ---- ph5: 10 reduce instances over 8 waves ----
    for (int p = w; p < OUTD; p += 8) {
        const float4 q0 = *(const float4*)&PP[p * 512 + l * 8];
        const float4 q1 = *(const float4*)&PP[p * 512 + l * 8 + 4];
        float v = (q0.x + q0.y) + (q0.z + q0.w) + (q1.x + q1.y) + (q1.z + q1.w);
        v += __shfl_down(v, 32, 64);
        v += __shfl_down(v, 16, 64);
        v += __shfl_down(v, 8, 64);
        v += __shfl_down(v, 4, 64);
        v += __shfl_down(v, 2, 64);
        v += __shfl_down(v, 1, 64);
        if (l == 0) out[(size_t)gidx * OUTD + p] = v + bias1[p];
    }
    __syncthreads();   // B6: PP reads done; region reusable for next graph
}

// ---------------------------------------------------------------------------
// Kernel 2: one block per TWO graphs processed sequentially, 512 threads.
// LDS: raw 32 KB (XtL 16K / GL 32K / PP 20K time-multiplexed) + sp 4 KB +
//      sS 0.5 KB = 37.4 KB -> 4 blocks/CU. Live AGPRs <= 32.
// ---------------------------------------------------------------------------
__global__ __launch_bounds__(512)
void graph_kernel(const float* __restrict__ x,
                  const __bf16* __restrict__ Sp,
                  const float* __restrict__ cg,
                  const float* __restrict__ bias1,
                  float* __restrict__ out)
{
    __shared__ __align__(16) char ldsraw[32 * 1024];
    __shared__ float sp[8][DD];                           // 4 KB
    __shared__ float sS[DD];                              // 512 B

    __bf16* const XtL = (__bf16*)ldsraw;
    __bf16* const GL  = (__bf16*)ldsraw;
    float*  const PP  = (float*)ldsraw;                   // 20 KB in ph4/5

    const int g0  = blockIdx.x * 2;
    const int tid = threadIdx.x;
    const int w   = tid >> 6;
    const int l   = tid & 63;
    const int l31 = l & 31;
    const int l5  = l >> 5;

    do_graph(x + (size_t)g0 * NN * DD, XtL, GL, PP, sp, sS,
             Sp, cg, bias1, out, g0, tid, w, l, l31, l5);
    do_graph(x + (size_t)(g0 + 1) * NN * DD, XtL, GL, PP, sp, sS,
             Sp, cg, bias1, out, g0 + 1, tid, w, l, l31, l5);
}

// ---------------------------------------------------------------------------
extern "C" void kernel_launch(void* const* d_in, const int* in_sizes, int n_in,
                              void* d_out, int out_size, void* d_ws, size_t ws_size,
                              hipStream_t stream)
{
    const float* x     = (const float*)d_in[0];
    const float* Wa    = (const float*)d_in[1];
    const float* b_att = (const float*)d_in[2];
    const float* W1    = (const float*)d_in[3];
    const float* bias1 = (const float*)d_in[4];
    float* out = (float*)d_out;

    float*  A  = (float*)d_ws;                       // 163840 f32 (640 KB)
    float*  c  = A + (size_t)OUTD * DD * DD;         // 1280 f32
    __bf16* Sp = (__bf16*)(c + OUTD * DD);           // 102400 bf16 (200 KB)

    precompute_kernel<<<OUTD * DD, 128, 0, stream>>>(Wa, b_att, W1, A, c);
    pack_kernel<<<100, 256, 0, stream>>>(A, Sp);
    graph_kernel<<<NG / 2, 512, 0, stream>>>(x, Sp, c, bias1, out);
}

// Round 14
// 48.630 us; speedup vs baseline: 1.9876x; 1.7277x over previous
//
#include <hip/hip_runtime.h>

typedef __attribute__((ext_vector_type(8)))  __bf16    bf16x8;
typedef __attribute__((ext_vector_type(4)))  __bf16    bf16x4;
typedef __attribute__((ext_vector_type(16))) float     f32x16;
typedef __attribute__((ext_vector_type(4)))  _Float16  f16x4;
typedef __attribute__((ext_vector_type(2)))  __fp16    h16x2;
typedef __attribute__((ext_vector_type(8)))  __fp16    h16x8;

constexpr int NG  = 2048;
constexpr int NN  = 64;
constexpr int DD  = 128;
constexpr int KK  = 128;
constexpr int OUTD = 10;

// upper-triangular 32x32 tile list: t -> (ti, tj), ti <= tj
__device__ __host__ inline void tileOf(int t, int& ti, int& tj) {
    if (t < 4)      { ti = 0; tj = t;     }
    else if (t < 7) { ti = 1; tj = t - 3; }
    else if (t < 9) { ti = 2; tj = t - 5; }
    else            { ti = 3; tj = 3;     }
}

// XtL: 64-elem rows -> XOR elem bits 3-5 with row&7
__device__ inline int xtIdx(int r, int c) { return r * 64  + (c ^ ((r & 7) << 3)); }
// GL: 128-elem rows -> XOR elem bits 3-6 with row&15
__device__ inline int gIdx (int r, int c) { return r * 128 + (c ^ ((r & 15) << 3)); }

#if __has_builtin(__builtin_amdgcn_fdot2)
__device__ __forceinline__ float dot2f(h16x2 a, h16x2 b, float c) {
    return __builtin_amdgcn_fdot2(a, b, c, false);
}
#else
__device__ __forceinline__ float dot2f(h16x2 a, h16x2 b, float c) {
    return c + (float)a[0] * (float)b[0] + (float)a[1] * (float)b[1];
}
#endif

// ---------------------------------------------------------------------------
// Kernel 1a: A[o][f][e] = sum_k Wa[k,f]*W1[o,k*D+e]; c[o][e] = sum_k b[k]*W1[o,k*D+e]
// ---------------------------------------------------------------------------
__global__ __launch_bounds__(128)
void precompute_kernel(const float* __restrict__ Wa,
                       const float* __restrict__ b_att,
                       const float* __restrict__ W1,
                       float* __restrict__ A,
                       float* __restrict__ c)
{
    const int o = blockIdx.x >> 7;
    const int f = blockIdx.x & 127;
    const int e = threadIdx.x;
    const float* __restrict__ W1o = W1 + (size_t)o * (KK * DD);

    float acc = 0.f, cacc = 0.f;
    for (int k = 0; k < KK; ++k) {
        const float w1 = W1o[k * DD + e];
        acc  += Wa[k * DD + f] * w1;
        cacc += b_att[k] * w1;
    }
    A[((size_t)o * DD + f) * DD + e] = acc;
    if (f == 0) c[o * DD + e] = cacc;
}

// ---------------------------------------------------------------------------
// Kernel 1b: symmetrized S packed in 32x32 D-fragment order, f16 (RNE),
// diag-tile upper part zeroed in memory.
//   Sp[((o*10+t)*64 + lane)*16 + r] = S[ti*32 + (r&3)+8*(r>>2)+4*(lane>>5), tj*32 + (lane&31)]
// ---------------------------------------------------------------------------
__global__ __launch_bounds__(256)
void pack_kernel(const float* __restrict__ A, _Float16* __restrict__ Sp)
{
    const int b = blockIdx.x;
    const int o = b / 10, t = b - o * 10;
    int ti, tj; tileOf(t, ti, tj);
    const int l  = threadIdx.x & 63;
    const int rq = threadIdx.x >> 6;      // 0..3
    const int e  = tj * 32 + (l & 31);
    const float* __restrict__ Ao = A + (size_t)o * DD * DD;

    f16x4 p;
#pragma unroll
    for (int j = 0; j < 4; ++j) {
        const int f = ti * 32 + j + 8 * rq + 4 * (l >> 5);
        float v;
        if (f < e)       v = Ao[f * DD + e] + Ao[e * DD + f];
        else if (f == e) v = Ao[f * DD + f];
        else             v = 0.f;
        p[j] = (_Float16)v;
    }
    *(f16x4*)&Sp[(size_t)((o * 10 + t) * 64 + l) * 16 + rq * 4] = p;
}

// ---------------------------------------------------------------------------
// Per-graph phases 0-3 (R7-proven). Produces colsum sOut[128] (waves 2,3),
// hacc0 (tile w), and accumulates extra tiles 8,9 into haccX on waves
// extraBase, extraBase+1 (haccX shared between graphs on disjoint wave pairs).
// ---------------------------------------------------------------------------
__device__ __forceinline__ void process_graph(
    const float* __restrict__ xg,
    __bf16* __restrict__ XtL, __bf16* __restrict__ GL,
    float (*__restrict__ sp)[DD], float* __restrict__ sOut,
    int tid, int w, int l, int l31, int l5, int extraBase,
    f32x16& hacc0, f32x16& haccX)
{
    // ---- phase 0: load X column-wise, store X^T as bf16 (RNE) ----
    {
        const int f = tid & 127, half = tid >> 7;
#pragma unroll
        for (int ch = 0; ch < 2; ++ch) {
            float v[8];
#pragma unroll
            for (int i = 0; i < 8; ++i) v[i] = xg[(half * 16 + ch * 8 + i) * DD + f];
            bf16x8 p;
#pragma unroll
            for (int i = 0; i < 8; ++i) p[i] = (__bf16)v[i];
            *(bf16x8*)&XtL[xtIdx(f, half * 16 + ch * 8)] = p;
        }
    }
    __syncthreads();

    // ---- phase 1: gram tiles. wave w: ti = w&3, tj = {2*(w>>2), +1} ----
    const int ti  = w & 3;
    const int tj0 = (w >> 2) * 2;
    f32x16 acc0, acc1;
#pragma unroll
    for (int i = 0; i < 16; ++i) { acc0[i] = 0.f; acc1[i] = 0.f; }
    {
        const int arow  = ti  * 32 + l31;
        const int brow0 = tj0 * 32 + l31;
#pragma unroll
        for (int ks = 0; ks < 4; ++ks) {
            const int kc = ks * 16 + l5 * 8;
            bf16x8 a  = *(const bf16x8*)&XtL[xtIdx(arow, kc)];
            bf16x8 b0 = *(const bf16x8*)&XtL[xtIdx(brow0, kc)];
            bf16x8 b1 = *(const bf16x8*)&XtL[xtIdx(brow0 + 32, kc)];
            acc0 = __builtin_amdgcn_mfma_f32_32x32x16_bf16(a, b0, acc0, 0, 0, 0);
            acc1 = __builtin_amdgcn_mfma_f32_32x32x16_bf16(a, b1, acc1, 0, 0, 0);
        }
    }
    __syncthreads();   // XtL reads done; GL may overwrite

    // ---- phase 2: quantize, store G transposed (symmetric) + column partials ----
    {
        float sum0 = 0.f, sum1 = 0.f;
#pragma unroll
        for (int tt = 0; tt < 2; ++tt) {
            const int e = (tj0 + tt) * 32 + l31;       // row of G (transposed write)
#pragma unroll
            for (int g2 = 0; g2 < 4; ++g2) {
                bf16x4 p;
#pragma unroll
                for (int j = 0; j < 4; ++j) {
                    const float av = tt ? acc1[g2 * 4 + j] : acc0[g2 * 4 + j];
                    const float q = rintf(av * 100.f) * 0.01f;
                    p[j] = (__bf16)q;
                    if (tt) sum1 += q; else sum0 += q;
                }
                const int fbase = ti * 32 + g2 * 8 + l5 * 4;
                *(bf16x4*)&GL[gIdx(e, fbase)] = p;
            }
        }
        sp[ti * 2 + l5][tj0 * 32 + l31]       = sum0;
        sp[ti * 2 + l5][(tj0 + 1) * 32 + l31] = sum1;
    }
    __syncthreads();   // G + sp complete

    // ---- phase 2.5 (waves 2,3): gather colsum ----
    if (w == 2 || w == 3) {
        const int e = (w - 2) * 64 + l;
        float s = 0.f;
#pragma unroll
        for (int i = 0; i < 8; ++i) s += sp[i][e];
        sOut[e] = s;
    }

    // ---- phase 3: H = G*G upper-tri tiles (extras 8,9 on extraBase,+1) ----
#pragma unroll
    for (int i = 0; i < 16; ++i) hacc0[i] = 0.f;
    {
        int hti, htj; tileOf(w, hti, htj);
        const int ra = hti * 32 + l31, rb = htj * 32 + l31;
#pragma unroll
        for (int ks = 0; ks < 8; ++ks) {
            const int kc = ks * 16 + l5 * 8;
            bf16x8 a = *(const bf16x8*)&GL[gIdx(ra, kc)];
            bf16x8 b = *(const bf16x8*)&GL[gIdx(rb, kc)];
            hacc0 = __builtin_amdgcn_mfma_f32_32x32x16_bf16(a, b, hacc0, 0, 0, 0);
        }
    }
    if (w == extraBase || w == extraBase + 1) {
        int ti1, tj1; tileOf(8 + (w - extraBase), ti1, tj1);
        const int ra = ti1 * 32 + l31, rb = tj1 * 32 + l31;
#pragma unroll
        for (int ks = 0; ks < 8; ++ks) {
            const int kc = ks * 16 + l5 * 8;
            bf16x8 a = *(const bf16x8*)&GL[gIdx(ra, kc)];
            bf16x8 b = *(const bf16x8*)&GL[gIdx(rb, kc)];
            haccX = __builtin_amdgcn_mfma_f32_32x32x16_bf16(a, b, haccX, 0, 0, 0);
        }
    }
    __syncthreads();   // GL reads done (region reusable); sOut visible
}

// ---------------------------------------------------------------------------
// Kernel 2: one block per TWO graphs, 512 threads = 8 waves (R7 structure).
// LDS: ldsraw 40 KB (XtL 16K -> GL 32K -> PP 40K), sp 4 KB, sA/sB 1 KB.
// Extra H-tiles: graph A on waves 6,7; graph B on waves 4,5 (shared hX1).
// ph4: f16 Sp + v_dot2_f32_f16; H-accs converted once to packed half2.
// ---------------------------------------------------------------------------
__global__ __launch_bounds__(512)
void graph_kernel(const float* __restrict__ x,
                  const _Float16* __restrict__ Sp,
                  const float* __restrict__ cg,
                  const float* __restrict__ bias1,
                  float* __restrict__ out)
{
    __shared__ __align__(16) char ldsraw[20 * 512 * 4];   // 40 KB
    __shared__ float sp[8][DD];                           // 4 KB
    __shared__ float sA[DD], sB[DD];

    __bf16* const XtL = (__bf16*)ldsraw;
    __bf16* const GL  = (__bf16*)ldsraw;
    float*  const PP  = (float*)ldsraw;

    const int g0  = blockIdx.x * 2;
    const int g1  = g0 + 1;
    const int tid = threadIdx.x;
    const int w   = tid >> 6;
    const int l   = tid & 63;
    const int l31 = l & 31;
    const int l5  = l >> 5;

    f32x16 hA0, hB0, hX1;
#pragma unroll
    for (int i = 0; i < 16; ++i) hX1[i] = 0.f;

    process_graph(x + (size_t)g0 * NN * DD, XtL, GL, sp, sA,
                  tid, w, l, l31, l5, /*extraBase=*/6, hA0, hX1);
    process_graph(x + (size_t)g1 * NN * DD, XtL, GL, sp, sB,
                  tid, w, l, l31, l5, /*extraBase=*/4, hB0, hX1);

    // ---- convert H accumulators to packed half2 (AGPRs die here) ----
    h16x2 hA[8], hB[8], hX[8];
#pragma unroll
    for (int i = 0; i < 8; ++i) {
        hA[i] = __builtin_amdgcn_cvt_pkrtz(hA0[2 * i], hA0[2 * i + 1]);
        hB[i] = __builtin_amdgcn_cvt_pkrtz(hB0[2 * i], hB0[2 * i + 1]);
        hX[i] = __builtin_amdgcn_cvt_pkrtz(hX1[2 * i], hX1[2 * i + 1]);
    }

    // ---- phase 4: contraction with Sp (f16, fragment order; zeros baked) ----
#pragma unroll
    for (int o = 0; o < OUTD; ++o) {
        const _Float16* __restrict__ spp = Sp + (size_t)((o * 10 + w) * 64 + l) * 16;
        const h16x8 s0 = *(const h16x8*)&spp[0];
        const h16x8 s1 = *(const h16x8*)&spp[8];
        float tA = 0.f, tB = 0.f;
#pragma unroll
        for (int i = 0; i < 4; ++i) {
            const h16x2 p = { s0[2 * i], s0[2 * i + 1] };
            tA = dot2f(p, hA[i], tA);
            tB = dot2f(p, hB[i], tB);
        }
#pragma unroll
        for (int i = 0; i < 4; ++i) {
            const h16x2 p = { s1[2 * i], s1[2 * i + 1] };
            tA = dot2f(p, hA[4 + i], tA);
            tB = dot2f(p, hB[4 + i], tB);
        }
        if (w >= 4) {   // extra tiles: t2 = 8+(w&1); A on waves 6,7 / B on 4,5
            const _Float16* __restrict__ sp2 =
                Sp + (size_t)((o * 10 + 8 + (w & 1)) * 64 + l) * 16;
            const h16x8 e0 = *(const h16x8*)&sp2[0];
            const h16x8 e1 = *(const h16x8*)&sp2[8];
            float tx = 0.f;
#pragma unroll
            for (int i = 0; i < 4; ++i) {
                const h16x2 p = { e0[2 * i], e0[2 * i + 1] };
                tx = dot2f(p, hX[i], tx);
            }
#pragma unroll
            for (int i = 0; i < 4; ++i) {
                const h16x2 p = { e1[2 * i], e1[2 * i + 1] };
                tx = dot2f(p, hX[4 + i], tx);
            }
            if (w >= 6) tA += tx; else tB += tx;
        }
        if (w == 0) {
            tA += cg[o * DD + l] * sA[l] + cg[o * DD + 64 + l] * sA[64 + l];
            tB += cg[o * DD + l] * sB[l] + cg[o * DD + 64 + l] * sB[64 + l];
        }
        PP[o * 512 + tid]        = tA;
        PP[(10 + o) * 512 + tid] = tB;
    }
    __syncthreads();

    // ---- phase 5: 20 reduce instances over 8 waves ----
    for (int p = w; p < 2 * OUTD; p += 8) {
        const float4 q0 = *(const float4*)&PP[p * 512 + l * 8];
        const float4 q1 = *(const float4*)&PP[p * 512 + l * 8 + 4];
        float v = (q0.x + q0.y) + (q0.z + q0.w) + (q1.x + q1.y) + (q1.z + q1.w);
        v += __shfl_down(v, 32, 64);
        v += __shfl_down(v, 16, 64);
        v += __shfl_down(v, 8, 64);
        v += __shfl_down(v, 4, 64);
        v += __shfl_down(v, 2, 64);
        v += __shfl_down(v, 1, 64);
        if (l == 0) {
            const int gg = (p < OUTD) ? g0 : g1;
            const int oo = (p < OUTD) ? p : p - OUTD;
            out[(size_t)gg * OUTD + oo] = v + bias1[oo];
        }
    }
}

// ---------------------------------------------------------------------------
extern "C" void kernel_launch(void* const* d_in, const int* in_sizes, int n_in,
                              void* d_out, int out_size, void* d_ws, size_t ws_size,
                              hipStream_t stream)
{
    const float* x     = (const float*)d_in[0];
    const float* Wa    = (const float*)d_in[1];
    const float* b_att = (const float*)d_in[2];
    const float* W1    = (const float*)d_in[3];
    const float* bias1 = (const float*)d_in[4];
    float* out = (float*)d_out;

    float*    A  = (float*)d_ws;                       // 163840 f32 (640 KB)
    float*    c  = A + (size_t)OUTD * DD * DD;         // 1280 f32
    _Float16* Sp = (_Float16*)(c + OUTD * DD);         // 102400 f16 (200 KB)

    precompute_kernel<<<OUTD * DD, 128, 0, stream>>>(Wa, b_att, W1, A, c);
    pack_kernel<<<100, 256, 0, stream>>>(A, Sp);
    graph_kernel<<<NG / 2, 512, 0, stream>>>(x, Sp, c, bias1, out);
}

// Round 15
// 43.227 us; speedup vs baseline: 2.2360x; 1.1250x over previous
//
#include <hip/hip_runtime.h>

typedef __attribute__((ext_vector_type(8)))  __bf16    bf16x8;
typedef __attribute__((ext_vector_type(4)))  __bf16    bf16x4;
typedef __attribute__((ext_vector_type(16))) float     f32x16;
typedef __attribute__((ext_vector_type(4)))  _Float16  f16x4;
typedef __attribute__((ext_vector_type(2)))  __fp16    h16x2;
typedef __attribute__((ext_vector_type(8)))  __fp16    h16x8;

constexpr int NG  = 2048;
constexpr int NN  = 64;
constexpr int DD  = 128;
constexpr int KK  = 128;
constexpr int OUTD = 10;

// upper-triangular 32x32 tile list: t -> (ti, tj), ti <= tj
__device__ __host__ inline void tileOf(int t, int& ti, int& tj) {
    if (t < 4)      { ti = 0; tj = t;     }
    else if (t < 7) { ti = 1; tj = t - 3; }
    else if (t < 9) { ti = 2; tj = t - 5; }
    else            { ti = 3; tj = 3;     }
}

// XtL: 64-elem rows -> XOR elem bits 3-5 with row&7
__device__ inline int xtIdx(int r, int c) { return r * 64  + (c ^ ((r & 7) << 3)); }
// GL: 128-elem rows -> XOR elem bits 3-6 with row&15
__device__ inline int gIdx (int r, int c) { return r * 128 + (c ^ ((r & 15) << 3)); }

#if __has_builtin(__builtin_amdgcn_fdot2)
__device__ __forceinline__ float dot2f(h16x2 a, h16x2 b, float c) {
    return __builtin_amdgcn_fdot2(a, b, c, false);
}
#else
__device__ __forceinline__ float dot2f(h16x2 a, h16x2 b, float c) {
    return c + (float)a[0] * (float)b[0] + (float)a[1] * (float)b[1];
}
#endif

// ---------------------------------------------------------------------------
// Fused setup kernel: one block per (o, tile). Computes the two 32x32 A-tiles
// needed for S tile t directly from Wa/W1 (same ascending-k f32 FMA chain as
// the old precompute_kernel -> bit-identical values), then packs Sp (f16,
// D-fragment order, diag zeros baked). ti==0 blocks also emit cg.
//   Sp[((o*10+t)*64 + lane)*16 + r] = S[ti*32 + (r&3)+8*(r>>2)+4*(lane>>5), tj*32 + (lane&31)]
// ---------------------------------------------------------------------------
__global__ __launch_bounds__(256)
void fused_sp_kernel(const float* __restrict__ Wa,
                     const float* __restrict__ b_att,
                     const float* __restrict__ W1,
                     _Float16* __restrict__ Sp,
                     float* __restrict__ cgout)
{
    const int blk = blockIdx.x;
    const int o = blk / 10, t = blk - o * 10;
    int ti, tj; tileOf(t, ti, tj);
    const int Fi = ti * 32, Ej = tj * 32;
    const float* __restrict__ W1o = W1 + (size_t)o * (KK * DD);

    __shared__ float WaF[KK][32];   // Wa[k][Fi+j]
    __shared__ float WaE[KK][32];   // Wa[k][Ej+j]
    __shared__ float W1F[KK][32];   // W1o[k][Fi+j]
    __shared__ float W1E[KK][32];   // W1o[k][Ej+j]
    __shared__ float AFE[32][33];   // A[Fi+f][Ej+e]  (padded)
    __shared__ float AEF[32][33];   // A[Ej+e][Fi+f]  (padded)
    __shared__ float bsh[KK];

    const int tid = threadIdx.x;

    // ---- stage panels (coalesced 128B rows) ----
    for (int r0 = 0; r0 < KK; r0 += 8) {
        const int r = r0 + (tid >> 5), cc = tid & 31;
        WaF[r][cc] = Wa[r * DD + Fi + cc];
        WaE[r][cc] = Wa[r * DD + Ej + cc];
        W1F[r][cc] = W1o[r * DD + Fi + cc];
        W1E[r][cc] = W1o[r * DD + Ej + cc];
    }
    if (tid < KK) bsh[tid] = b_att[tid];
    __syncthreads();

    // ---- compute A tiles: thread -> row (tid>>3), 4 cols ((tid&7)*4) ----
    {
        const int rloc = tid >> 3;          // 0..31
        const int q    = (tid & 7) * 4;     // 0,4,..,28
        float a0 = 0.f, a1 = 0.f, a2 = 0.f, a3 = 0.f;
        float b0 = 0.f, b1 = 0.f, b2 = 0.f, b3 = 0.f;
        for (int k = 0; k < KK; ++k) {
            const float av = WaF[k][rloc];
            const float4 wv = *(const float4*)&W1E[k][q];
            a0 += av * wv.x; a1 += av * wv.y; a2 += av * wv.z; a3 += av * wv.w;
            const float bv = WaE[k][rloc];
            const float4 vv = *(const float4*)&W1F[k][q];
            b0 += bv * vv.x; b1 += bv * vv.y; b2 += bv * vv.z; b3 += bv * vv.w;
        }
        AFE[rloc][q] = a0; AFE[rloc][q + 1] = a1; AFE[rloc][q + 2] = a2; AFE[rloc][q + 3] = a3;
        AEF[rloc][q] = b0; AEF[rloc][q + 1] = b1; AEF[rloc][q + 2] = b2; AEF[rloc][q + 3] = b3;
    }
    __syncthreads();

    // ---- pack S tile (proven indexing) ----
    {
        const int l  = tid & 63;
        const int rq = tid >> 6;            // 0..3
        const int eg = l & 31;              // e local
        const int e  = Ej + eg;
        f16x4 p;
#pragma unroll
        for (int j = 0; j < 4; ++j) {
            const int fl = j + 8 * rq + 4 * (l >> 5);
            const int f  = Fi + fl;
            float v;
            if (f < e)       v = AFE[fl][eg] + AEF[eg][fl];
            else if (f == e) v = AFE[fl][eg];
            else             v = 0.f;
            p[j] = (_Float16)v;
        }
        *(f16x4*)&Sp[(size_t)((o * 10 + t) * 64 + l) * 16 + rq * 4] = p;
    }

    // ---- cg (ti==0 blocks cover all e via tj=0..3) ----
    if (ti == 0 && tid < 32) {
        float s = 0.f;
        for (int k = 0; k < KK; ++k) s += bsh[k] * W1E[k][tid];
        cgout[o * DD + Ej + tid] = s;
    }
}

// ---------------------------------------------------------------------------
// Per-graph phases 0-3 (R7-proven). Produces colsum sOut[128] (waves 2,3),
// hacc0 (tile w), and accumulates extra tiles 8,9 into haccX on waves
// extraBase, extraBase+1 (haccX shared between graphs on disjoint wave pairs).
// ---------------------------------------------------------------------------
__device__ __forceinline__ void process_graph(
    const float* __restrict__ xg,
    __bf16* __restrict__ XtL, __bf16* __restrict__ GL,
    float (*__restrict__ sp)[DD], float* __restrict__ sOut,
    int tid, int w, int l, int l31, int l5, int extraBase,
    f32x16& hacc0, f32x16& haccX)
{
    // ---- phase 0: load X column-wise, store X^T as bf16 (RNE) ----
    {
        const int f = tid & 127, half = tid >> 7;
#pragma unroll
        for (int ch = 0; ch < 2; ++ch) {
            float v[8];
#pragma unroll
            for (int i = 0; i < 8; ++i) v[i] = xg[(half * 16 + ch * 8 + i) * DD + f];
            bf16x8 p;
#pragma unroll
            for (int i = 0; i < 8; ++i) p[i] = (__bf16)v[i];
            *(bf16x8*)&XtL[xtIdx(f, half * 16 + ch * 8)] = p;
        }
    }
    __syncthreads();

    // ---- phase 1: gram tiles. wave w: ti = w&3, tj = {2*(w>>2), +1} ----
    const int ti  = w & 3;
    const int tj0 = (w >> 2) * 2;
    f32x16 acc0, acc1;
#pragma unroll
    for (int i = 0; i < 16; ++i) { acc0[i] = 0.f; acc1[i] = 0.f; }
    {
        const int arow  = ti  * 32 + l31;
        const int brow0 = tj0 * 32 + l31;
#pragma unroll
        for (int ks = 0; ks < 4; ++ks) {
            const int kc = ks * 16 + l5 * 8;
            bf16x8 a  = *(const bf16x8*)&XtL[xtIdx(arow, kc)];
            bf16x8 b0 = *(const bf16x8*)&XtL[xtIdx(brow0, kc)];
            bf16x8 b1 = *(const bf16x8*)&XtL[xtIdx(brow0 + 32, kc)];
            acc0 = __builtin_amdgcn_mfma_f32_32x32x16_bf16(a, b0, acc0, 0, 0, 0);
            acc1 = __builtin_amdgcn_mfma_f32_32x32x16_bf16(a, b1, acc1, 0, 0, 0);
        }
    }
    __syncthreads();   // XtL reads done; GL may overwrite

    // ---- phase 2: quantize, store G transposed (symmetric) + column partials ----
    {
        float sum0 = 0.f, sum1 = 0.f;
#pragma unroll
        for (int tt = 0; tt < 2; ++tt) {
            const int e = (tj0 + tt) * 32 + l31;       // row of G (transposed write)
#pragma unroll
            for (int g2 = 0; g2 < 4; ++g2) {
                bf16x4 p;
#pragma unroll
                for (int j = 0; j < 4; ++j) {
                    const float av = tt ? acc1[g2 * 4 + j] : acc0[g2 * 4 + j];
                    const float q = rintf(av * 100.f) * 0.01f;
                    p[j] = (__bf16)q;
                    if (tt) sum1 += q; else sum0 += q;
                }
                const int fbase = ti * 32 + g2 * 8 + l5 * 4;
                *(bf16x4*)&GL[gIdx(e, fbase)] = p;
            }
        }
        sp[ti * 2 + l5][tj0 * 32 + l31]       = sum0;
        sp[ti * 2 + l5][(tj0 + 1) * 32 + l31] = sum1;
    }
    __syncthreads();   // G + sp complete

    // ---- phase 2.5 (waves 2,3): gather colsum ----
    if (w == 2 || w == 3) {
        const int e = (w - 2) * 64 + l;
        float s = 0.f;
#pragma unroll
        for (int i = 0; i < 8; ++i) s += sp[i][e];
        sOut[e] = s;
    }

    // ---- phase 3: H = G*G upper-tri tiles (extras 8,9 on extraBase,+1) ----
#pragma unroll
    for (int i = 0; i < 16; ++i) hacc0[i] = 0.f;
    {
        int hti, htj; tileOf(w, hti, htj);
        const int ra = hti * 32 + l31, rb = htj * 32 + l31;
#pragma unroll
        for (int ks = 0; ks < 8; ++ks) {
            const int kc = ks * 16 + l5 * 8;
            bf16x8 a = *(const bf16x8*)&GL[gIdx(ra, kc)];
            bf16x8 b = *(const bf16x8*)&GL[gIdx(rb, kc)];
            hacc0 = __builtin_amdgcn_mfma_f32_32x32x16_bf16(a, b, hacc0, 0, 0, 0);
        }
    }
    if (w == extraBase || w == extraBase + 1) {
        int ti1, tj1; tileOf(8 + (w - extraBase), ti1, tj1);
        const int ra = ti1 * 32 + l31, rb = tj1 * 32 + l31;
#pragma unroll
        for (int ks = 0; ks < 8; ++ks) {
            const int kc = ks * 16 + l5 * 8;
            bf16x8 a = *(const bf16x8*)&GL[gIdx(ra, kc)];
            bf16x8 b = *(const bf16x8*)&GL[gIdx(rb, kc)];
            haccX = __builtin_amdgcn_mfma_f32_32x32x16_bf16(a, b, haccX, 0, 0, 0);
        }
    }
    __syncthreads();   // GL reads done (region reusable); sOut visible
}

// ---------------------------------------------------------------------------
// Kernel 2 (R14-proven, untouched): one block per TWO graphs, 512 threads.
// LDS: ldsraw 40 KB (XtL 16K -> GL 32K -> PP 40K), sp 4 KB, sA/sB 1 KB.
// Extra H-tiles: graph A on waves 6,7; graph B on waves 4,5 (shared hX1).
// ph4: f16 Sp + v_dot2_f32_f16; H-accs converted once to packed half2.
// ---------------------------------------------------------------------------
__global__ __launch_bounds__(512)
void graph_kernel(const float* __restrict__ x,
                  const _Float16* __restrict__ Sp,
                  const float* __restrict__ cg,
                  const float* __restrict__ bias1,
                  float* __restrict__ out)
{
    __shared__ __align__(16) char ldsraw[20 * 512 * 4];   // 40 KB
    __shared__ float sp[8][DD];                           // 4 KB
    __shared__ float sA[DD], sB[DD];

    __bf16* const XtL = (__bf16*)ldsraw;
    __bf16* const GL  = (__bf16*)ldsraw;
    float*  const PP  = (float*)ldsraw;

    const int g0  = blockIdx.x * 2;
    const int g1  = g0 + 1;
    const int tid = threadIdx.x;
    const int w   = tid >> 6;
    const int l   = tid & 63;
    const int l31 = l & 31;
    const int l5  = l >> 5;

    f32x16 hA0, hB0, hX1;
#pragma unroll
    for (int i = 0; i < 16; ++i) hX1[i] = 0.f;

    process_graph(x + (size_t)g0 * NN * DD, XtL, GL, sp, sA,
                  tid, w, l, l31, l5, /*extraBase=*/6, hA0, hX1);
    process_graph(x + (size_t)g1 * NN * DD, XtL, GL, sp, sB,
                  tid, w, l, l31, l5, /*extraBase=*/4, hB0, hX1);

    // ---- convert H accumulators to packed half2 (AGPRs die here) ----
    h16x2 hA[8], hB[8], hX[8];
#pragma unroll
    for (int i = 0; i < 8; ++i) {
        hA[i] = __builtin_amdgcn_cvt_pkrtz(hA0[2 * i], hA0[2 * i + 1]);
        hB[i] = __builtin_amdgcn_cvt_pkrtz(hB0[2 * i], hB0[2 * i + 1]);
        hX[i] = __builtin_amdgcn_cvt_pkrtz(hX1[2 * i], hX1[2 * i + 1]);
    }

    // ---- phase 4: contraction with Sp (f16, fragment order; zeros baked) ----
#pragma unroll
    for (int o = 0; o < OUTD; ++o) {
        const _Float16* __restrict__ spp = Sp + (size_t)((o * 10 + w) * 64 + l) * 16;
        const h16x8 s0 = *(const h16x8*)&spp[0];
        const h16x8 s1 = *(const h16x8*)&spp[8];
        float tA = 0.f, tB = 0.f;
#pragma unroll
        for (int i = 0; i < 4; ++i) {
            const h16x2 p = { s0[2 * i], s0[2 * i + 1] };
            tA = dot2f(p, hA[i], tA);
            tB = dot2f(p, hB[i], tB);
        }
#pragma unroll
        for (int i = 0; i < 4; ++i) {
            const h16x2 p = { s1[2 * i], s1[2 * i + 1] };
            tA = dot2f(p, hA[4 + i], tA);
            tB = dot2f(p, hB[4 + i], tB);
        }
        if (w >= 4) {   // extra tiles: t2 = 8+(w&1); A on waves 6,7 / B on 4,5
            const _Float16* __restrict__ sp2 =
                Sp + (size_t)((o * 10 + 8 + (w & 1)) * 64 + l) * 16;
            const h16x8 e0 = *(const h16x8*)&sp2[0];
            const h16x8 e1 = *(const h16x8*)&sp2[8];
            float tx = 0.f;
#pragma unroll
            for (int i = 0; i < 4; ++i) {
                const h16x2 p = { e0[2 * i], e0[2 * i + 1] };
                tx = dot2f(p, hX[i], tx);
            }
#pragma unroll
            for (int i = 0; i < 4; ++i) {
                const h16x2 p = { e1[2 * i], e1[2 * i + 1] };
                tx = dot2f(p, hX[4 + i], tx);
            }
            if (w >= 6) tA += tx; else tB += tx;
        }
        if (w == 0) {
            tA += cg[o * DD + l] * sA[l] + cg[o * DD + 64 + l] * sA[64 + l];
            tB += cg[o * DD + l] * sB[l] + cg[o * DD + 64 + l] * sB[64 + l];
        }
        PP[o * 512 + tid]        = tA;
        PP[(10 + o) * 512 + tid] = tB;
    }
    __syncthreads();

    // ---- phase 5: 20 reduce instances over 8 waves ----
    for (int p = w; p < 2 * OUTD; p += 8) {
        const float4 q0 = *(const float4*)&PP[p * 512 + l * 8];
        const float4 q1 = *(const float4*)&PP[p * 512 + l * 8 + 4];
        float v = (q0.x + q0.y) + (q0.z + q0.w) + (q1.x + q1.y) + (q1.z + q1.w);
        v += __shfl_down(v, 32, 64);
        v += __shfl_down(v, 16, 64);
        v += __shfl_down(v, 8, 64);
        v += __shfl_down(v, 4, 64);
        v += __shfl_down(v, 2, 64);
        v += __shfl_down(v, 1, 64);
        if (l == 0) {
            const int gg = (p < OUTD) ? g0 : g1;
            const int oo = (p < OUTD) ? p : p - OUTD;
            out[(size_t)gg * OUTD + oo] = v + bias1[oo];
        }
    }
}

// ---------------------------------------------------------------------------
extern "C" void kernel_launch(void* const* d_in, const int* in_sizes, int n_in,
                              void* d_out, int out_size, void* d_ws, size_t ws_size,
                              hipStream_t stream)
{
    const float* x     = (const float*)d_in[0];
    const float* Wa    = (const float*)d_in[1];
    const float* b_att = (const float*)d_in[2];
    const float* W1    = (const float*)d_in[3];
    const float* bias1 = (const float*)d_in[4];
    float* out = (float*)d_out;

    float*    cg = (float*)d_ws;                     // 1280 f32 (5 KB)
    _Float16* Sp = (_Float16*)(cg + OUTD * DD);      // 102400 f16 (200 KB)

    fused_sp_kernel<<<100, 256, 0, stream>>>(Wa, b_att, W1, Sp, cg);
    graph_kernel<<<NG / 2, 512, 0, stream>>>(x, Sp, cg, bias1, out);
}